// Round 12
// baseline (2926.490 us; speedup 1.0000x reference)
//
#include <hip/hip_runtime.h>
#include <cstdint>
#include <cstddef>

// Problem: B=64, T=512, I=128, H=256, 4H=1024, C=3. All fp32 in/out.
typedef _Float16 half2_t __attribute__((ext_vector_type(2)));
typedef _Float16 half8_t __attribute__((ext_vector_type(8)));
typedef float f32x4 __attribute__((ext_vector_type(4)));

static __device__ __forceinline__ float fdot2(half2_t a, half2_t b, float c) {
    return __builtin_amdgcn_fdot2(a, b, c, false);
}
static __device__ __forceinline__ half2_t h2(unsigned int u) {
    return __builtin_bit_cast(half2_t, u);
}
static __device__ __forceinline__ float sigm(float x) {
    return 1.f / (1.f + __expf(-x));
}
static __device__ __forceinline__ float tanh_fast(float x) {
    float ax = fabsf(x);
    float e = __expf(2.f * ax);
    float r = 1.f - 2.f / (e + 1.f);
    return copysignf(r, x);
}

// ---------------------------------------------------------------------------
// prep: W_hh (1024x256 fp32) -> f16 plane layout for the v18 scan.
// plane p = g*32+u (g=gate 0..3, u=chunk 0..31), entry j (0..255):
//   Wp[p*256+j] = 8 halves of W[g*256+j][u*8 ..]
// bias = b_ih + b_hh
// ---------------------------------------------------------------------------
__global__ __launch_bounds__(256) void prep_whh(const float* __restrict__ Whh,
                                                const float* __restrict__ bih,
                                                const float* __restrict__ bhh,
                                                uint4* __restrict__ Wp,
                                                float* __restrict__ bias) {
    int n = blockIdx.x * 256 + threadIdx.x;  // 0..32767
    if (n < 1024) bias[n] = bih[n] + bhh[n];
    int p = n >> 8;         // plane 0..127
    int j = n & 255;
    int g = p >> 5, u = p & 31;
    int row = g * 256 + j;
    int kb = u * 8;
    union { uint4 u4; _Float16 h[8]; } cv;
#pragma unroll
    for (int i = 0; i < 8; ++i) cv.h[i] = (_Float16)Whh[row * 256 + kb + i];
    Wp[p * 256 + j] = cv.u4;
}

// f32 -> f16, 4 elements/thread
__global__ __launch_bounds__(256) void cvt_f16(const float* __restrict__ in,
                                               _Float16* __restrict__ out, int n4) {
    int i = blockIdx.x * 256 + threadIdx.x;
    if (i < n4) {
        float4 v = ((const float4*)in)[i];
        union { ushort4 u; _Float16 h[4]; } cv;
        cv.h[0] = (_Float16)v.x; cv.h[1] = (_Float16)v.y;
        cv.h[2] = (_Float16)v.z; cv.h[3] = (_Float16)v.w;
        ((ushort4*)out)[i] = cv.u;
    }
}

// ---------------------------------------------------------------------------
// gemm_mfma: C[M][1024] = A[M][K](f16) * W[1024][K](f16)^T + bias, fp32 out.
// ---------------------------------------------------------------------------
__global__ __launch_bounds__(256) void gemm_mfma(const _Float16* __restrict__ A,
                                                 const _Float16* __restrict__ Bw,
                                                 const float* __restrict__ bias,
                                                 float* __restrict__ Cmat, int K) {
    __shared__ _Float16 As[64][72];
    __shared__ _Float16 Bs[64][72];
    const int tid = threadIdx.x;
    const int wave = tid >> 6, lane = tid & 63;
    const int quad = lane >> 4, l16 = lane & 15;
    const int m0 = blockIdx.x * 64, n0 = blockIdx.y * 64;
    const int sr = tid >> 2;
    const int sc = (tid & 3) * 16;

    f32x4 acc[4] = {};

    for (int k0 = 0; k0 < K; k0 += 64) {
        const uint4 a0v = *(const uint4*)(A + (size_t)(m0 + sr) * K + k0 + sc);
        const uint4 a1v = *(const uint4*)(A + (size_t)(m0 + sr) * K + k0 + sc + 8);
        const uint4 b0v = *(const uint4*)(Bw + (size_t)(n0 + sr) * K + k0 + sc);
        const uint4 b1v = *(const uint4*)(Bw + (size_t)(n0 + sr) * K + k0 + sc + 8);
        __syncthreads();
        *(uint4*)&As[sr][sc] = a0v;
        *(uint4*)&As[sr][sc + 8] = a1v;
        *(uint4*)&Bs[sr][sc] = b0v;
        *(uint4*)&Bs[sr][sc + 8] = b1v;
        __syncthreads();
#pragma unroll
        for (int kc = 0; kc < 64; kc += 32) {
            half8_t af = *(const half8_t*)&As[wave * 16 + l16][kc + quad * 8];
#pragma unroll
            for (int nb = 0; nb < 4; ++nb) {
                half8_t bf = *(const half8_t*)&Bs[nb * 16 + l16][kc + quad * 8];
                acc[nb] = __builtin_amdgcn_mfma_f32_16x16x32_f16(af, bf, acc[nb], 0, 0, 0);
            }
        }
    }
#pragma unroll
    for (int nb = 0; nb < 4; ++nb) {
#pragma unroll
        for (int i = 0; i < 4; ++i) {
            int row = m0 + wave * 16 + quad * 4 + i;
            int col = n0 + nb * 16 + l16;
            Cmat[(size_t)row * 1024 + col] = acc[nb][i] + bias[col];
        }
    }
}

// ---------------------------------------------------------------------------
// lstm_scan v18: 64 WGs x 256 thr (4 waves = 1 wave/SIMD -> ~512-reg budget).
// Thread j owns ALL FOUR gate rows {j, 256+j, 512+j, 768+j} over the FULL
// K=256 (32 chunks): complete gate pre-activations are thread-local, so
// there is NO exchange (pex gone) and only ONE lgkm-only barrier per step.
// Weights/thread = 128 uint4: 104 in registers (416 regs: gates i,f,g
// fully + o chunks 0..7), 24 streamed from LDS (96 KB, gate-o chunks 8..31).
// LDS wave-ops/step: h 32x4=128 (uniform b128 broadcast) + w 24x4=96 + ~4
// writes = ~228 vs v11's ~280 -- and the pex round-trip + barrier are gone.
// hist has 16 slots: flush(t) reads slots s0..s0+7 while step t+1 writes
// slot (t+1)&15 in the OTHER ring half -> race-free across the single
// barrier. Fallback if VGPR spill appears: wreg=96.
// ---------------------------------------------------------------------------
__global__ __launch_bounds__(256, 1)
void lstm_scan(const float* __restrict__ gx,
               const uint4* __restrict__ Wp,
               _Float16* __restrict__ h_out,
               int store_all) {
    const int b = blockIdx.x;
    const int j = threadIdx.x;     // hidden unit 0..255

    __shared__ uint4 wlds[24 * 256];                                 // 96 KB
    __shared__ _Float16 hbuf[2][256] __attribute__((aligned(16)));   // 1 KB
    __shared__ _Float16 hist[16][256] __attribute__((aligned(16)));  // 8 KB

    // stage gate-o chunks 8..31 (planes 104..127) into LDS
#pragma unroll
    for (int p = 0; p < 24; ++p) wlds[p * 256 + j] = Wp[(104 + p) * 256 + j];
    // persistent register weights: planes 0..103 (i, f, g, o[0..7])
    uint4 wreg[104];
#pragma unroll
    for (int p = 0; p < 104; ++p) wreg[p] = Wp[p * 256 + j];

    hbuf[0][j] = (_Float16)0.f;
    float c = 0.f;
    _Float16 last_h = (_Float16)0.f;
    // gx rows for unit j: gates i,f,g,o at rows j, 256+j, 512+j, 768+j
    const float* gxb = gx + (size_t)b * 512 * 1024 + j;
    float g0 = gxb[0], g1 = gxb[256], g2 = gxb[512], g3 = gxb[768];
    __syncthreads();  // one-time full sync: wlds + hbuf[0] visible

    for (int t = 0; t < 512; ++t) {
        // prefetch next step's gx (stays in flight across the barrier)
        float n0 = 0.f, n1 = 0.f, n2 = 0.f, n3 = 0.f;
        if (t < 511) {
            const float* gxn = gxb + (size_t)(t + 1) * 1024;
            n0 = gxn[0]; n1 = gxn[256]; n2 = gxn[512]; n3 = gxn[768];
        }

        const uint4* hb = (const uint4*)&hbuf[t & 1][0];
        // 2-deep pipelines: hv (uniform h chunks), ws (streamed gate-o)
        uint4 hv0 = hb[0], hv1 = hb[1];
        uint4 ws0 = wlds[0 * 256 + j], ws1 = wlds[1 * 256 + j];

        float a0 = 0.f, a1 = 0.f, a2 = 0.f, a3 = 0.f;
#pragma unroll
        for (int u = 0; u < 32; ++u) {
            const uint4 hv = (u & 1) ? hv1 : hv0;
            if (u + 2 < 32) {
                if (u & 1) hv1 = hb[u + 2]; else hv0 = hb[u + 2];
            }
            const uint4 w3 = (u < 8) ? wreg[96 + u] : ((u & 1) ? ws1 : ws0);
            if (u >= 8 && u < 30) {
                // prefetch streamed chunk u-6 (consumed at u+2)
                if (u & 1) ws1 = wlds[(u - 6) * 256 + j];
                else       ws0 = wlds[(u - 6) * 256 + j];
            }
            const uint4 w0 = wreg[u];          // gate i
            const uint4 w1 = wreg[32 + u];     // gate f
            const uint4 w2 = wreg[64 + u];     // gate g
            a0 = fdot2(h2(w0.x), h2(hv.x), a0);
            a1 = fdot2(h2(w1.x), h2(hv.x), a1);
            a2 = fdot2(h2(w2.x), h2(hv.x), a2);
            a3 = fdot2(h2(w3.x), h2(hv.x), a3);
            a0 = fdot2(h2(w0.y), h2(hv.y), a0);
            a1 = fdot2(h2(w1.y), h2(hv.y), a1);
            a2 = fdot2(h2(w2.y), h2(hv.y), a2);
            a3 = fdot2(h2(w3.y), h2(hv.y), a3);
            a0 = fdot2(h2(w0.z), h2(hv.z), a0);
            a1 = fdot2(h2(w1.z), h2(hv.z), a1);
            a2 = fdot2(h2(w2.z), h2(hv.z), a2);
            a3 = fdot2(h2(w3.z), h2(hv.z), a3);
            a0 = fdot2(h2(w0.w), h2(hv.w), a0);
            a1 = fdot2(h2(w1.w), h2(hv.w), a1);
            a2 = fdot2(h2(w2.w), h2(hv.w), a2);
            a3 = fdot2(h2(w3.w), h2(hv.w), a3);
        }
        a0 += g0; a1 += g1; a2 += g2; a3 += g3;

        // complete gate set is thread-local: no exchange needed
        const float iv = sigm(a0);
        const float fv = sigm(a1);
        const float gv = tanh_fast(a2);
        const float ov = sigm(a3);
        c = fv * c + iv * gv;
        const _Float16 hh = (_Float16)(ov * tanh_fast(c));
        hbuf[(t + 1) & 1][j] = hh;
        last_h = hh;
        if (store_all) hist[t & 15][j] = hh;
        g0 = n0; g1 = n1; g2 = n2; g3 = n3;

        // single barrier: LDS visibility only; globals stay in flight.
        // WAR-safe: hbuf[t&1] is next written at step t+1 (after this
        // barrier for every wave); hist flush region is the other ring half.
        asm volatile("s_waitcnt lgkmcnt(0)" ::: "memory");
        __builtin_amdgcn_s_barrier();
        asm volatile("" ::: "memory");

        if (store_all && (t & 7) == 7) {
            // flush 8 steps (4 KB) with 256 threads (16 B each)
            const int s0 = (t - 7) & 15;  // 0 or 8 (ring half)
            const uint4 v = *(const uint4*)((const char*)hist + s0 * 512 + j * 16);
            *(uint4*)(h_out + (size_t)b * 512 * 256 + (size_t)(t - 7) * 256 + j * 8) = v;
        }
    }
    if (!store_all) {
        h_out[(size_t)b * 256 + j] = last_h;  // compact last-h for the FC
    }
}

// ---------------------------------------------------------------------------
// fc_softmax: logits = hlast[b,:](f16) @ fc_w^T + fc_b, softmax over 3
// ---------------------------------------------------------------------------
__global__ __launch_bounds__(64) void fc_softmax(const _Float16* __restrict__ hlast,
                                                 const float* __restrict__ fcw,
                                                 const float* __restrict__ fcb,
                                                 float* __restrict__ out) {
    const int b = blockIdx.x;
    const int lane = threadIdx.x;
    const _Float16* h = hlast + (size_t)b * 256;
    float p0 = 0.f, p1 = 0.f, p2 = 0.f;
    for (int k = lane; k < 256; k += 64) {
        float hv = (float)h[k];
        p0 += hv * fcw[k];
        p1 += hv * fcw[256 + k];
        p2 += hv * fcw[512 + k];
    }
#pragma unroll
    for (int off = 32; off > 0; off >>= 1) {
        p0 += __shfl_down(p0, off);
        p1 += __shfl_down(p1, off);
        p2 += __shfl_down(p2, off);
    }
    if (lane == 0) {
        float l0 = p0 + fcb[0], l1 = p1 + fcb[1], l2 = p2 + fcb[2];
        float m = fmaxf(l0, fmaxf(l1, l2));
        float e0 = __expf(l0 - m), e1 = __expf(l1 - m), e2 = __expf(l2 - m);
        float s = 1.f / (e0 + e1 + e2);
        out[b * 3 + 0] = e0 * s;
        out[b * 3 + 1] = e1 * s;
        out[b * 3 + 2] = e2 * s;
    }
}

extern "C" void kernel_launch(void* const* d_in, const int* in_sizes, int n_in,
                              void* d_out, int out_size, void* d_ws, size_t ws_size,
                              hipStream_t stream) {
    const float* x    = (const float*)d_in[0];
    const float* Wih0 = (const float*)d_in[1];
    const float* Whh0 = (const float*)d_in[2];
    const float* bih0 = (const float*)d_in[3];
    const float* bhh0 = (const float*)d_in[4];
    const float* Wih1 = (const float*)d_in[5];
    const float* Whh1 = (const float*)d_in[6];
    const float* bih1 = (const float*)d_in[7];
    const float* bhh1 = (const float*)d_in[8];
    const float* fcw  = (const float*)d_in[9];
    const float* fcb  = (const float*)d_in[10];
    float* out = (float*)d_out;

    // workspace layout (~161 MB)
    char* ws = (char*)d_ws;
    float* gx        = (float*)ws;     ws += (size_t)32768 * 1024 * 4;  // 134.2 MB
    _Float16* h0f    = (_Float16*)ws;  ws += (size_t)32768 * 256 * 2;   // 16.8 MB
    _Float16* xh     = (_Float16*)ws;  ws += (size_t)32768 * 128 * 2;   // 8.4 MB
    _Float16* hlast  = (_Float16*)ws;  ws += (size_t)64 * 256 * 2;      // 32 KB
    _Float16* Wih0h  = (_Float16*)ws;  ws += (size_t)1024 * 128 * 2;    // 256 KB
    _Float16* Wih1h  = (_Float16*)ws;  ws += (size_t)1024 * 256 * 2;    // 512 KB
    uint4* Wp0       = (uint4*)ws;     ws += (size_t)1024 * 256 * 2;    // 512 KB
    uint4* Wp1       = (uint4*)ws;     ws += (size_t)1024 * 256 * 2;    // 512 KB
    float* bias0     = (float*)ws;     ws += 4096;
    float* bias1     = (float*)ws;     ws += 4096;

    prep_whh<<<128, 256, 0, stream>>>(Whh0, bih0, bhh0, Wp0, bias0);
    prep_whh<<<128, 256, 0, stream>>>(Whh1, bih1, bhh1, Wp1, bias1);
    cvt_f16<<<4096, 256, 0, stream>>>(x, xh, 32768 * 128 / 4);
    cvt_f16<<<128, 256, 0, stream>>>(Wih0, Wih0h, 1024 * 128 / 4);
    cvt_f16<<<256, 256, 0, stream>>>(Wih1, Wih1h, 1024 * 256 / 4);

    // layer 0
    gemm_mfma<<<dim3(512, 16), 256, 0, stream>>>(xh, Wih0h, bias0, gx, 128);
    lstm_scan<<<64, 256, 0, stream>>>(gx, Wp0, h0f, 1);

    // layer 1
    gemm_mfma<<<dim3(512, 16), 256, 0, stream>>>(h0f, Wih1h, bias1, gx, 256);
    lstm_scan<<<64, 256, 0, stream>>>(gx, Wp1, hlast, 0);

    fc_softmax<<<64, 64, 0, stream>>>(hlast, fcw, fcb, out);
}

// Round 13
// 1952.915 us; speedup vs baseline: 1.4985x; 1.4985x over previous
//
#include <hip/hip_runtime.h>
#include <cstdint>
#include <cstddef>

// Problem: B=64, T=512, I=128, H=256, 4H=1024, C=3. All fp32 in/out.
typedef _Float16 half2_t __attribute__((ext_vector_type(2)));
typedef _Float16 half8_t __attribute__((ext_vector_type(8)));
typedef float f32x4 __attribute__((ext_vector_type(4)));

static __device__ __forceinline__ float fdot2(half2_t a, half2_t b, float c) {
    return __builtin_amdgcn_fdot2(a, b, c, false);
}
static __device__ __forceinline__ half2_t h2(unsigned int u) {
    return __builtin_bit_cast(half2_t, u);
}
static __device__ __forceinline__ float sigm(float x) {
    return 1.f / (1.f + __expf(-x));
}
static __device__ __forceinline__ float tanh_fast(float x) {
    float ax = fabsf(x);
    float e = __expf(2.f * ax);
    float r = 1.f - 2.f / (e + 1.f);
    return copysignf(r, x);
}
static __device__ __forceinline__ float dot4(const uint4 w, const uint4 h, float a) {
    a = fdot2(h2(w.x), h2(h.x), a);
    a = fdot2(h2(w.y), h2(h.y), a);
    a = fdot2(h2(w.z), h2(h.z), a);
    a = fdot2(h2(w.w), h2(h.w), a);
    return a;
}

// ---------------------------------------------------------------------------
// prep: W_hh (1024x256 fp32) -> f16 plane layout for the v19 scan.
// plane p = m*8+cc (m=row-block 0..7, cc=K-chunk-in-quarter 0..7),
// entry e = kq*128 + sl (kq=K-quarter 0..3, sl=s*64+l):
//   Wp[p*512+e] = 8 halves of W[sl + 128*m][kq*64 + cc*8 ..]
// bias = b_ih + b_hh
// ---------------------------------------------------------------------------
__global__ __launch_bounds__(256) void prep_whh(const float* __restrict__ Whh,
                                                const float* __restrict__ bih,
                                                const float* __restrict__ bhh,
                                                uint4* __restrict__ Wp,
                                                float* __restrict__ bias) {
    int n = blockIdx.x * 256 + threadIdx.x;  // 0..32767
    if (n < 1024) bias[n] = bih[n] + bhh[n];
    int p = n >> 9;         // plane 0..63 = m*8+cc
    int e = n & 511;        // kq*128 + sl
    int m = p >> 3, cc = p & 7;
    int kq = e >> 7, sl = e & 127;
    int row = sl + 128 * m;
    int kb = kq * 64 + cc * 8;
    union { uint4 u4; _Float16 h[8]; } cv;
#pragma unroll
    for (int i = 0; i < 8; ++i) cv.h[i] = (_Float16)Whh[row * 256 + kb + i];
    Wp[p * 512 + e] = cv.u4;
}

// f32 -> f16, 4 elements/thread
__global__ __launch_bounds__(256) void cvt_f16(const float* __restrict__ in,
                                               _Float16* __restrict__ out, int n4) {
    int i = blockIdx.x * 256 + threadIdx.x;
    if (i < n4) {
        float4 v = ((const float4*)in)[i];
        union { ushort4 u; _Float16 h[4]; } cv;
        cv.h[0] = (_Float16)v.x; cv.h[1] = (_Float16)v.y;
        cv.h[2] = (_Float16)v.z; cv.h[3] = (_Float16)v.w;
        ((ushort4*)out)[i] = cv.u;
    }
}

// ---------------------------------------------------------------------------
// gemm_mfma: C[M][1024] = A[M][K](f16) * W[1024][K](f16)^T + bias, fp32 out.
// ---------------------------------------------------------------------------
__global__ __launch_bounds__(256) void gemm_mfma(const _Float16* __restrict__ A,
                                                 const _Float16* __restrict__ Bw,
                                                 const float* __restrict__ bias,
                                                 float* __restrict__ Cmat, int K) {
    __shared__ _Float16 As[64][72];
    __shared__ _Float16 Bs[64][72];
    const int tid = threadIdx.x;
    const int wave = tid >> 6, lane = tid & 63;
    const int quad = lane >> 4, l16 = lane & 15;
    const int m0 = blockIdx.x * 64, n0 = blockIdx.y * 64;
    const int sr = tid >> 2;
    const int sc = (tid & 3) * 16;

    f32x4 acc[4] = {};

    for (int k0 = 0; k0 < K; k0 += 64) {
        const uint4 a0v = *(const uint4*)(A + (size_t)(m0 + sr) * K + k0 + sc);
        const uint4 a1v = *(const uint4*)(A + (size_t)(m0 + sr) * K + k0 + sc + 8);
        const uint4 b0v = *(const uint4*)(Bw + (size_t)(n0 + sr) * K + k0 + sc);
        const uint4 b1v = *(const uint4*)(Bw + (size_t)(n0 + sr) * K + k0 + sc + 8);
        __syncthreads();
        *(uint4*)&As[sr][sc] = a0v;
        *(uint4*)&As[sr][sc + 8] = a1v;
        *(uint4*)&Bs[sr][sc] = b0v;
        *(uint4*)&Bs[sr][sc + 8] = b1v;
        __syncthreads();
#pragma unroll
        for (int kc = 0; kc < 64; kc += 32) {
            half8_t af = *(const half8_t*)&As[wave * 16 + l16][kc + quad * 8];
#pragma unroll
            for (int nb = 0; nb < 4; ++nb) {
                half8_t bf = *(const half8_t*)&Bs[nb * 16 + l16][kc + quad * 8];
                acc[nb] = __builtin_amdgcn_mfma_f32_16x16x32_f16(af, bf, acc[nb], 0, 0, 0);
            }
        }
    }
#pragma unroll
    for (int nb = 0; nb < 4; ++nb) {
#pragma unroll
        for (int i = 0; i < 4; ++i) {
            int row = m0 + wave * 16 + quad * 4 + i;
            int col = n0 + nb * 16 + l16;
            Cmat[(size_t)row * 1024 + col] = acc[nb][i] + bias[col];
        }
    }
}

// ---------------------------------------------------------------------------
// lstm_scan v19: 64 WGs x 512 thr (8 waves, 2 waves/SIMD, 256-reg budget).
// K-QUARTER remap on the v11 skeleton: wave w -> K-quarter kq=w&3
// (wave-uniform), row-set s=w>>2. Thread (kq,sl=s*64+l) computes partials
// of 8 rows {sl+128m, m=0..7} over K-slice [kq*64, kq*64+64) = 8 chunks.
// LDS budget/step (wave-ops): h 8x8=64 (was 128: the quarter is REUSED by
// all 8 rows), weights 16/thread -> 128 (48 planes reg / 16 planes LDS,
// unchanged), pex ~48 (repacked [kq][mhalf][sl] float4: write 2xb128,
// read 8xb128 consecutive-lane -> conflict-free), writes ~8: total ~248
// vs v11's ~280. Counted lgkm-only barriers (v11's proven pattern).
// gx folded via wave-uniform kq branches (no dynamic a[] indexing).
// ---------------------------------------------------------------------------
__global__ __launch_bounds__(512, 2)
void lstm_scan(const float* __restrict__ gx,
               const uint4* __restrict__ Wp,
               _Float16* __restrict__ h_out,
               int store_all) {
    const int tid = threadIdx.x;
    const int b = blockIdx.x;
    const int w = tid >> 6, l = tid & 63;
    const int kq = w & 3;          // K-quarter (wave-uniform)
    const int s = w >> 2;          // row-set 0/1
    const int sl = s * 64 + l;     // 0..127
    const int e = kq * 128 + sl;   // plane-entry index = gx row1

    __shared__ uint4 wlds[16 * 512];                                 // 128 KB
    __shared__ float pex[4 * 2 * 128 * 4] __attribute__((aligned(16)));  // 16 KB
    __shared__ _Float16 hbuf[2][256] __attribute__((aligned(16)));   // 1 KB
    __shared__ _Float16 hist[8][256] __attribute__((aligned(16)));   // 4 KB

    // stage streamed planes (m=6,7 -> p=48..63) into LDS at [p-48][tid]
#pragma unroll
    for (int p = 0; p < 16; ++p) wlds[p * 512 + tid] = Wp[(48 + p) * 512 + e];
    // persistent register weights: planes 0..47 (m=0..5)
    uint4 wreg[48];
#pragma unroll
    for (int p = 0; p < 48; ++p) wreg[p] = Wp[p * 512 + e];

    if (tid < 256) hbuf[0][tid] = (_Float16)0.f;
    float c = 0.f;
    // gx rows folded by this thread: row1 = e (-> a[kq]), row2 = e+512 (-> a[kq+4])
    const float* gxb = gx + (size_t)b * 512 * 1024;
    float gA = gxb[e], gB = gxb[e + 512];
    __syncthreads();  // one-time full sync: wlds + hbuf[0] visible

    f32x4* pexv = (f32x4*)pex;
    const int jh = (tid & 255) >> 7;  // updater row-half (wave-uniform)
    const int js = tid & 127;

    for (int t = 0; t < 512; ++t) {
        // prefetch next step's gx (stays in flight across barriers)
        float gA_n = 0.f, gB_n = 0.f;
        if (t < 511) {
            gA_n = gxb[(size_t)(t + 1) * 1024 + e];
            gB_n = gxb[(size_t)(t + 1) * 1024 + e + 512];
        }

        // this wave's K-quarter of h: 8 uniform uint4 chunks
        const uint4* hb = (const uint4*)&hbuf[t & 1][0] + kq * 8;

        // streamed-weight pipeline: consumption order (m6,cc),(m7,cc), cc=0..7
        uint4 wsP = wlds[0 * 512 + tid];   // (m6, cc=0)
        uint4 wsQ = wlds[8 * 512 + tid];   // (m7, cc=0)

        float a0 = 0.f, a1 = 0.f, a2 = 0.f, a3 = 0.f;
        float a4 = 0.f, a5 = 0.f, a6 = 0.f, a7 = 0.f;
#pragma unroll
        for (int cc = 0; cc < 8; ++cc) {
            const uint4 hv = hb[cc];
            const uint4 w6 = wsP, w7 = wsQ;
            if (cc < 7) {
                wsP = wlds[(cc + 1) * 512 + tid];
                wsQ = wlds[(9 + cc) * 512 + tid];
            }
            a0 = dot4(wreg[cc],      hv, a0);
            a1 = dot4(wreg[8 + cc],  hv, a1);
            a2 = dot4(wreg[16 + cc], hv, a2);
            a3 = dot4(wreg[24 + cc], hv, a3);
            a4 = dot4(wreg[32 + cc], hv, a4);
            a5 = dot4(wreg[40 + cc], hv, a5);
            a6 = dot4(w6, hv, a6);
            a7 = dot4(w7, hv, a7);
        }
        // fold gx into the quarter that owns it (wave-uniform branch)
        if (kq == 0)      { a0 += gA; a4 += gB; }
        else if (kq == 1) { a1 += gA; a5 += gB; }
        else if (kq == 2) { a2 += gA; a6 += gB; }
        else              { a3 += gA; a7 += gB; }

        // pex[kq][mh][sl] as float4
        f32x4 lo = {a0, a1, a2, a3};
        f32x4 hi = {a4, a5, a6, a7};
        pexv[(kq * 2 + 0) * 128 + sl] = lo;
        pexv[(kq * 2 + 1) * 128 + sl] = hi;
        gA = gA_n; gB = gB_n;
        // barrier1: pex visible; all hbuf[t&1] reads done. NO vmcnt drain.
        asm volatile("s_waitcnt lgkmcnt(0)" ::: "memory");
        __builtin_amdgcn_s_barrier();
        asm volatile("" ::: "memory");

        if (tid < 256) {
            const int j = tid;
            // row r = g*256+j -> m = g*2+jh, sl_row = j&127 = js
            float Ai = 0.f, Af = 0.f, Ag = 0.f, Ao = 0.f;
#pragma unroll
            for (int k2 = 0; k2 < 4; ++k2) {
                const f32x4 v0 = pexv[(k2 * 2 + 0) * 128 + js];  // m 0..3
                const f32x4 v1 = pexv[(k2 * 2 + 1) * 128 + js];  // m 4..7
                Ai += jh ? v0[1] : v0[0];   // m = jh
                Af += jh ? v0[3] : v0[2];   // m = 2+jh
                Ag += jh ? v1[1] : v1[0];   // m = 4+jh
                Ao += jh ? v1[3] : v1[2];   // m = 6+jh
            }
            const float iv = sigm(Ai);
            const float fv = sigm(Af);
            const float gv = tanh_fast(Ag);
            const float ov = sigm(Ao);
            c = fv * c + iv * gv;
            const _Float16 hh = (_Float16)(ov * tanh_fast(c));
            hbuf[(t + 1) & 1][j] = hh;
            if (store_all) hist[t & 7][j] = hh;
        }
        // barrier2: new h + hist visible. NO vmcnt drain.
        asm volatile("s_waitcnt lgkmcnt(0)" ::: "memory");
        __builtin_amdgcn_s_barrier();
        asm volatile("" ::: "memory");

        if (store_all && (t & 7) == 7) {
            // flush 8 steps (4 KB) with all 512 threads (8 B each);
            // the global store stays in flight past the next barriers
            const uint2 v = ((const uint2*)hist)[tid];
            *(uint2*)(h_out + (size_t)b * 512 * 256 + (size_t)(t - 7) * 256 + tid * 4) = v;
        }
    }
    if (!store_all && tid < 256) {
        // final h lives in hbuf[0] (512 & 1 == 0)
        h_out[(size_t)b * 256 + tid] = hbuf[0][tid];
    }
}

// ---------------------------------------------------------------------------
// fc_softmax: logits = hlast[b,:](f16) @ fc_w^T + fc_b, softmax over 3
// ---------------------------------------------------------------------------
__global__ __launch_bounds__(64) void fc_softmax(const _Float16* __restrict__ hlast,
                                                 const float* __restrict__ fcw,
                                                 const float* __restrict__ fcb,
                                                 float* __restrict__ out) {
    const int b = blockIdx.x;
    const int lane = threadIdx.x;
    const _Float16* h = hlast + (size_t)b * 256;
    float p0 = 0.f, p1 = 0.f, p2 = 0.f;
    for (int k = lane; k < 256; k += 64) {
        float hv = (float)h[k];
        p0 += hv * fcw[k];
        p1 += hv * fcw[256 + k];
        p2 += hv * fcw[512 + k];
    }
#pragma unroll
    for (int off = 32; off > 0; off >>= 1) {
        p0 += __shfl_down(p0, off);
        p1 += __shfl_down(p1, off);
        p2 += __shfl_down(p2, off);
    }
    if (lane == 0) {
        float l0 = p0 + fcb[0], l1 = p1 + fcb[1], l2 = p2 + fcb[2];
        float m = fmaxf(l0, fmaxf(l1, l2));
        float e0 = __expf(l0 - m), e1 = __expf(l1 - m), e2 = __expf(l2 - m);
        float s = 1.f / (e0 + e1 + e2);
        out[b * 3 + 0] = e0 * s;
        out[b * 3 + 1] = e1 * s;
        out[b * 3 + 2] = e2 * s;
    }
}

extern "C" void kernel_launch(void* const* d_in, const int* in_sizes, int n_in,
                              void* d_out, int out_size, void* d_ws, size_t ws_size,
                              hipStream_t stream) {
    const float* x    = (const float*)d_in[0];
    const float* Wih0 = (const float*)d_in[1];
    const float* Whh0 = (const float*)d_in[2];
    const float* bih0 = (const float*)d_in[3];
    const float* bhh0 = (const float*)d_in[4];
    const float* Wih1 = (const float*)d_in[5];
    const float* Whh1 = (const float*)d_in[6];
    const float* bih1 = (const float*)d_in[7];
    const float* bhh1 = (const float*)d_in[8];
    const float* fcw  = (const float*)d_in[9];
    const float* fcb  = (const float*)d_in[10];
    float* out = (float*)d_out;

    // workspace layout (~161 MB)
    char* ws = (char*)d_ws;
    float* gx        = (float*)ws;     ws += (size_t)32768 * 1024 * 4;  // 134.2 MB
    _Float16* h0f    = (_Float16*)ws;  ws += (size_t)32768 * 256 * 2;   // 16.8 MB
    _Float16* xh     = (_Float16*)ws;  ws += (size_t)32768 * 128 * 2;   // 8.4 MB
    _Float16* hlast  = (_Float16*)ws;  ws += (size_t)64 * 256 * 2;      // 32 KB
    _Float16* Wih0h  = (_Float16*)ws;  ws += (size_t)1024 * 128 * 2;    // 256 KB
    _Float16* Wih1h  = (_Float16*)ws;  ws += (size_t)1024 * 256 * 2;    // 512 KB
    uint4* Wp0       = (uint4*)ws;     ws += (size_t)1024 * 256 * 2;    // 512 KB
    uint4* Wp1       = (uint4*)ws;     ws += (size_t)1024 * 256 * 2;    // 512 KB
    float* bias0     = (float*)ws;     ws += 4096;
    float* bias1     = (float*)ws;     ws += 4096;

    prep_whh<<<128, 256, 0, stream>>>(Whh0, bih0, bhh0, Wp0, bias0);
    prep_whh<<<128, 256, 0, stream>>>(Whh1, bih1, bhh1, Wp1, bias1);
    cvt_f16<<<4096, 256, 0, stream>>>(x, xh, 32768 * 128 / 4);
    cvt_f16<<<128, 256, 0, stream>>>(Wih0, Wih0h, 1024 * 128 / 4);
    cvt_f16<<<256, 256, 0, stream>>>(Wih1, Wih1h, 1024 * 256 / 4);

    // layer 0
    gemm_mfma<<<dim3(512, 16), 256, 0, stream>>>(xh, Wih0h, bias0, gx, 128);
    lstm_scan<<<64, 512, 0, stream>>>(gx, Wp0, h0f, 1);

    // layer 1
    gemm_mfma<<<dim3(512, 16), 256, 0, stream>>>(h0f, Wih1h, bias1, gx, 256);
    lstm_scan<<<64, 512, 0, stream>>>(gx, Wp1, hlast, 0);

    fc_softmax<<<64, 64, 0, stream>>>(hlast, fcw, fcb, out);
}